// Round 21
// baseline (33.785 us; speedup 1.0000x reference)
//
#include <hip/hip_runtime.h>
#include <hip/hip_bf16.h>

#define L_SEQ 1024
#define NT 32          // number of 32-row KV tiles

typedef __attribute__((ext_vector_type(8))) __bf16 bf16x8;
typedef __attribute__((ext_vector_type(4))) __bf16 bf16x4;
typedef __attribute__((ext_vector_type(4))) float f32x4;

__device__ __forceinline__ float fast_exp2(float x) {
#if __has_builtin(__builtin_amdgcn_exp2f)
    return __builtin_amdgcn_exp2f(x);
#else
    return exp2f(x);
#endif
}

#define MFMA16(a, b, c) __builtin_amdgcn_mfma_f32_16x16x32_bf16((a), (b), (c), 0, 0, 0)

// ---------------------------------------------------------------------------
// Round 21: R19 + DEPTH-2 register staging (ping-pong sets A/B).
// R19's schedule issued load(t+2) after writebuf(t+1) and consumed it at the
// NEXT iteration's writebuf -> slack = body+barrier only; an HBM-latency miss
// stalls writebuf right after the barrier and serializes into every wave's
// iteration. Here tile t's load is issued TWO iterations before its writebuf
// (even tiles -> set A, odd -> set B), slack ~= 2 full iterations >> 900 cy.
// Cost: +8 VGPR. Everything else R19-verbatim: 512 blocks x 512 threads,
// 16 q-rows/wave, conflict-free K/V LDS images, de-fenced body, no-max exp2
// softmax (NBIAS in acc init), ones-MFMA l, single lgkmcnt(0)+barrier/iter.
// ---------------------------------------------------------------------------
__global__ __launch_bounds__(512) void sdpa_fused(
    const float* __restrict__ Q, const float* __restrict__ K,
    const float* __restrict__ V, float* __restrict__ O)
{
    __shared__ __align__(16) char lds[2 * 8192];

    const int tid  = threadIdx.x;
    const int lane = tid & 63;
    const int wave = tid >> 6;       // 0..7
    const int li   = lane & 15;
    const int h    = lane >> 4;

    // XCD-chunked swizzle: 64 consecutive logical blocks per XCD.
    const int wg = blockIdx.x;
    const int lb = (wg & 7) * 64 + (wg >> 3);
    const int b  = lb >> 3;          // batch
    const int qt = lb & 7;           // 128-row q-tile
    const int q0 = qt * 128 + wave * 16 + li;   // 8 waves cover 128 rows

    const float* Qb = Q + (size_t)b * L_SEQ * 64;
    const char*  Kb = (const char*)(K + (size_t)b * L_SEQ * 64);
    const float* Vf = V + (size_t)b * L_SEQ * 64;

    // ---- K staging dest offset (tile-invariant; R12 layout; 1 quad)
    int kd0;
    {
        const int qi = tid;                    // quad index 0..511
        const int r  = qi >> 4;                // kv row 0..31
        const int d4 = (qi & 15) << 2;         // d 0..60
        const int c32 = d4 >> 5, rem = d4 & 31, hf = rem >> 4, hh = (rem & 15) >> 2;
        kd0 = r * 128 + 2 * (((c32 * 32 + hh * 8) ^ ((r & 7) * 8)) + hf * 4);
    }
    // ---- V staging: column assignment + conflict-free b64 dest offset
    const int vd  = tid & 63;              // d column this thread owns
    const int vwd = 4096 + vd * 64 + 8 * (wave ^ ((vd >> 1) & 7));
    // rows covered: wave*4 .. wave*4+3

    // ---- Q fragments (single q-block): fold (1/temperature)*log2(e)
    const float QSC = 0.18033688011112042f;   // 0.125 * log2(e)
    bf16x8 qf0, qf1;
    {
        const float* ra = &Qb[(size_t)q0 * 64];
        f32x4 a00 = *(const f32x4*)&ra[0  + h * 4];
        f32x4 a01 = *(const f32x4*)&ra[16 + h * 4];
        f32x4 a10 = *(const f32x4*)&ra[32 + h * 4];
        f32x4 a11 = *(const f32x4*)&ra[48 + h * 4];
        #pragma unroll
        for (int j = 0; j < 4; ++j) {
            qf0[j]     = (__bf16)(a00[j] * QSC);
            qf0[4 + j] = (__bf16)(a01[j] * QSC);
            qf1[j]     = (__bf16)(a10[j] * QSC);
            qf1[4 + j] = (__bf16)(a11[j] * QSC);
        }
    }

    bf16x8 ones;
    #pragma unroll
    for (int j = 0; j < 8; ++j) ones[j] = (__bf16)1.0f;

    const float NBIAS = -46.0f;   // log2-domain bias, cancels in O = PV/l
    f32x4 o0 = {0.f,0.f,0.f,0.f}, o1 = {0.f,0.f,0.f,0.f};
    f32x4 o2 = {0.f,0.f,0.f,0.f}, o3 = {0.f,0.f,0.f,0.f};
    f32x4 ol = {0.f,0.f,0.f,0.f};

    // ---- depth-2 reg-staging: set A = even tiles, set B = odd tiles
    f32x4 skA, svA, skB, svB;
    auto loadA = [&](int t) {
        const size_t tb = (size_t)t * 8192;
        skA = *(const f32x4*)(Kb + tb + (tid << 4));
        const float* vcol = Vf + (size_t)t * 2048 + (size_t)(wave * 4) * 64 + vd;
        #pragma unroll
        for (int u = 0; u < 4; ++u) svA[u] = vcol[u * 64];
    };
    auto loadB = [&](int t) {
        const size_t tb = (size_t)t * 8192;
        skB = *(const f32x4*)(Kb + tb + (tid << 4));
        const float* vcol = Vf + (size_t)t * 2048 + (size_t)(wave * 4) * 64 + vd;
        #pragma unroll
        for (int u = 0; u < 4; ++u) svB[u] = vcol[u * 64];
    };
    auto writebufA = [&](int bi) {
        char* B = lds + bi * 8192;
        bf16x4 a, v0;
        #pragma unroll
        for (int j = 0; j < 4; ++j) { a[j] = (__bf16)skA[j]; v0[j] = (__bf16)svA[j]; }
        *(bf16x4*)(B + kd0) = a;
        *(bf16x4*)(B + vwd) = v0;
    };
    auto writebufB = [&](int bi) {
        char* B = lds + bi * 8192;
        bf16x4 a, v0;
        #pragma unroll
        for (int j = 0; j < 4; ++j) { a[j] = (__bf16)skB[j]; v0[j] = (__bf16)svB[j]; }
        *(bf16x4*)(B + kd0) = a;
        *(bf16x4*)(B + vwd) = v0;
    };

    const int kswz = (li & 7) << 4;
    const int swr  = (li >> 1) & 7;
    const int vo   = (h ^ swr) << 3;

    auto body = [&](int bi) {
        const char* bb = lds + bi * 8192;
        // K fragments (swizzled image)
        bf16x8 kf00 = *(const bf16x8*)(bb + li * 128 + ((h * 16) ^ kswz));
        bf16x8 kf01 = *(const bf16x8*)(bb + li * 128 + ((64 + h * 16) ^ kswz));
        bf16x8 kf10 = *(const bf16x8*)(bb + 2048 + li * 128 + ((h * 16) ^ kswz));
        bf16x8 kf11 = *(const bf16x8*)(bb + 2048 + li * 128 + ((64 + h * 16) ^ kswz));
        // V^T fragments: per chunk, 2 x ds_read_b64 (conflict-free, R15 map)
        bf16x8 vf[4];
        #pragma unroll
        for (int dc = 0; dc < 4; ++dc) {
            const char* vbase = bb + 4096 + (dc * 16 + li) * 64;
            bf16x4 lo = *(const bf16x4*)(vbase + vo);
            bf16x4 hi = *(const bf16x4*)(vbase + (vo ^ 32));
            vf[dc] = __builtin_shufflevector(lo, hi, 0, 1, 2, 3, 4, 5, 6, 7);
        }
        // de-fenced: compiler emits fine-grained lgkmcnt(N) per MFMA operand

        // ---- QK^T (bias pre-loaded in accumulator)
        const f32x4 nb = {NBIAS, NBIAS, NBIAS, NBIAS};
        f32x4 s0 = MFMA16(kf01, qf1, MFMA16(kf00, qf0, nb));
        f32x4 s1 = MFMA16(kf11, qf1, MFMA16(kf10, qf0, nb));

        // ---- exponentiate (no max, no cross-lane): p = 2^(s - 46)
        bf16x8 pf;
        #pragma unroll
        for (int r = 0; r < 4; ++r) {
            pf[r]     = (__bf16)fast_exp2(s0[r]);
            pf[4 + r] = (__bf16)fast_exp2(s1[r]);
        }

        // ---- PV + l via ones-MFMA
        o0 = MFMA16(vf[0], pf, o0);
        o1 = MFMA16(vf[1], pf, o1);
        o2 = MFMA16(vf[2], pf, o2);
        o3 = MFMA16(vf[3], pf, o3);
        ol = MFMA16(ones, pf, ol);
    };

    // end-of-iteration ordering point (single fence per iter)
    auto fence_barrier = [&]() {
        asm volatile("s_waitcnt lgkmcnt(0)" ::: "memory");
        __builtin_amdgcn_s_barrier();
    };

    // ---- prologue: tiles 0(A), 1(B) loaded; tile 0 written; tile 2(A) issued
    loadA(0);
    loadB(1);
    writebufA(0);        // one-time stall on tile 0's load
    loadA(2);
    fence_barrier();

    // 30 iterations (t = 0..29), two per loop trip (even t then odd t)
    for (int tt = 0; tt < 30; tt += 2) {
        // iter t = tt (even): write tile tt+1 (odd -> set B), refill B
        writebufB((tt + 1) & 1);         // buf 1
        loadB(tt + 3);                   // tiles 3,5,...,31
        body(tt & 1);                    // buf 0
        fence_barrier();
        // iter t = tt+1 (odd): write tile tt+2 (even -> set A), refill A
        writebufA((tt + 2) & 1);         // buf 0
        if (tt + 4 <= 31) loadA(tt + 4); // tiles 4,6,...,30 (skip 32)
        body((tt + 1) & 1);              // buf 1
        fence_barrier();
    }
    // t = 30: write tile 31 (set B, loaded at tt=28), no more loads
    writebufB(31 & 1);
    body(30 & 1);
    fence_barrier();
    // t = 31
    body(31 & 1);

    // ---- finalize: l replicated in ol[r] (ones-MFMA)
    const float inv_l = 1.f / ol[0];

    float* Ob = O + ((size_t)b * L_SEQ + q0) * 64;
    f32x4 ov;
    #pragma unroll
    for (int r = 0; r < 4; ++r) ov[r] = o0[r] * inv_l;
    *(f32x4*)&Ob[0 * 16 + h * 4] = ov;
    #pragma unroll
    for (int r = 0; r < 4; ++r) ov[r] = o1[r] * inv_l;
    *(f32x4*)&Ob[1 * 16 + h * 4] = ov;
    #pragma unroll
    for (int r = 0; r < 4; ++r) ov[r] = o2[r] * inv_l;
    *(f32x4*)&Ob[2 * 16 + h * 4] = ov;
    #pragma unroll
    for (int r = 0; r < 4; ++r) ov[r] = o3[r] * inv_l;
    *(f32x4*)&Ob[3 * 16 + h * 4] = ov;
}

extern "C" void kernel_launch(void* const* d_in, const int* in_sizes, int n_in,
                              void* d_out, int out_size, void* d_ws, size_t ws_size,
                              hipStream_t stream) {
    const float* q = (const float*)d_in[0];
    const float* k = (const float*)d_in[1];
    const float* v = (const float*)d_in[2];
    float* o = (float*)d_out;

    sdpa_fused<<<dim3(512), dim3(512), 0, stream>>>(q, k, v, o);
}

// Round 22
// 33.573 us; speedup vs baseline: 1.0063x; 1.0063x over previous
//
#include <hip/hip_runtime.h>
#include <hip/hip_bf16.h>

#define L_SEQ 1024
#define NT 32          // number of 32-row KV tiles

typedef __attribute__((ext_vector_type(8))) __bf16 bf16x8;
typedef __attribute__((ext_vector_type(4))) __bf16 bf16x4;
typedef __attribute__((ext_vector_type(4))) float f32x4;

__device__ __forceinline__ float fast_exp2(float x) {
#if __has_builtin(__builtin_amdgcn_exp2f)
    return __builtin_amdgcn_exp2f(x);
#else
    return exp2f(x);
#endif
}

#define MFMA16(a, b, c) __builtin_amdgcn_mfma_f32_16x16x32_bf16((a), (b), (c), 0, 0, 0)

// ---------------------------------------------------------------------------
// Round 22: R19 + s_setprio(1/0) around the MFMA clusters (T5, isolated).
// R14 removed setprio only as part of the de-fencing bundle; this re-adds it
// alone. Mechanism: with 16 waves/CU in 2 de-aligned blocks, waves are at
// different phases (staging VMEM/LDS vs MFMA); priority keeps the matrix
// pipe fed while siblings issue memory ops. Catalog: +4-7% on attention
// (m191) when phase diversity exists. Everything else R19-verbatim:
// 512 blocks x 512 threads, 16 q-rows/wave, conflict-free K/V LDS images,
// de-fenced body, no-max exp2 softmax (NBIAS in acc init), ones-MFMA l,
// single lgkmcnt(0)+barrier per iteration.
// ---------------------------------------------------------------------------
__global__ __launch_bounds__(512) void sdpa_fused(
    const float* __restrict__ Q, const float* __restrict__ K,
    const float* __restrict__ V, float* __restrict__ O)
{
    __shared__ __align__(16) char lds[2 * 8192];

    const int tid  = threadIdx.x;
    const int lane = tid & 63;
    const int wave = tid >> 6;       // 0..7
    const int li   = lane & 15;
    const int h    = lane >> 4;

    // XCD-chunked swizzle: 64 consecutive logical blocks per XCD.
    const int wg = blockIdx.x;
    const int lb = (wg & 7) * 64 + (wg >> 3);
    const int b  = lb >> 3;          // batch
    const int qt = lb & 7;           // 128-row q-tile
    const int q0 = qt * 128 + wave * 16 + li;   // 8 waves cover 128 rows

    const float* Qb = Q + (size_t)b * L_SEQ * 64;
    const char*  Kb = (const char*)(K + (size_t)b * L_SEQ * 64);
    const float* Vf = V + (size_t)b * L_SEQ * 64;

    // ---- K staging dest offset (tile-invariant; R12 layout; 1 quad)
    int kd0;
    {
        const int qi = tid;                    // quad index 0..511
        const int r  = qi >> 4;                // kv row 0..31
        const int d4 = (qi & 15) << 2;         // d 0..60
        const int c32 = d4 >> 5, rem = d4 & 31, hf = rem >> 4, hh = (rem & 15) >> 2;
        kd0 = r * 128 + 2 * (((c32 * 32 + hh * 8) ^ ((r & 7) * 8)) + hf * 4);
    }
    // ---- V staging: column assignment + conflict-free b64 dest offset
    const int vd  = tid & 63;              // d column this thread owns
    const int vwd = 4096 + vd * 64 + 8 * (wave ^ ((vd >> 1) & 7));
    // rows covered: wave*4 .. wave*4+3

    // ---- Q fragments (single q-block): fold (1/temperature)*log2(e)
    const float QSC = 0.18033688011112042f;   // 0.125 * log2(e)
    bf16x8 qf0, qf1;
    {
        const float* ra = &Qb[(size_t)q0 * 64];
        f32x4 a00 = *(const f32x4*)&ra[0  + h * 4];
        f32x4 a01 = *(const f32x4*)&ra[16 + h * 4];
        f32x4 a10 = *(const f32x4*)&ra[32 + h * 4];
        f32x4 a11 = *(const f32x4*)&ra[48 + h * 4];
        #pragma unroll
        for (int j = 0; j < 4; ++j) {
            qf0[j]     = (__bf16)(a00[j] * QSC);
            qf0[4 + j] = (__bf16)(a01[j] * QSC);
            qf1[j]     = (__bf16)(a10[j] * QSC);
            qf1[4 + j] = (__bf16)(a11[j] * QSC);
        }
    }

    bf16x8 ones;
    #pragma unroll
    for (int j = 0; j < 8; ++j) ones[j] = (__bf16)1.0f;

    const float NBIAS = -46.0f;   // log2-domain bias, cancels in O = PV/l
    f32x4 o0 = {0.f,0.f,0.f,0.f}, o1 = {0.f,0.f,0.f,0.f};
    f32x4 o2 = {0.f,0.f,0.f,0.f}, o3 = {0.f,0.f,0.f,0.f};
    f32x4 ol = {0.f,0.f,0.f,0.f};

    // ---- reg-staging: K = 1 float4 row-wise, V = 4 f32 column-wise
    f32x4 sk0, sv0;
    auto load = [&](int t) {
        const size_t tb = (size_t)t * 8192;    // bytes
        sk0 = *(const f32x4*)(Kb + tb + (tid << 4));
        const float* vcol = Vf + (size_t)t * 2048 + (size_t)(wave * 4) * 64 + vd;
        #pragma unroll
        for (int u = 0; u < 4; ++u) sv0[u] = vcol[u * 64];
    };
    auto writebuf = [&](int bi) {
        char* B = lds + bi * 8192;
        bf16x4 a, v0;
        #pragma unroll
        for (int j = 0; j < 4; ++j) { a[j] = (__bf16)sk0[j]; v0[j] = (__bf16)sv0[j]; }
        *(bf16x4*)(B + kd0) = a;
        *(bf16x4*)(B + vwd) = v0;
    };

    const int kswz = (li & 7) << 4;
    const int swr  = (li >> 1) & 7;
    const int vo   = (h ^ swr) << 3;

    auto body = [&](int bi) {
        const char* bb = lds + bi * 8192;
        // K fragments (swizzled image)
        bf16x8 kf00 = *(const bf16x8*)(bb + li * 128 + ((h * 16) ^ kswz));
        bf16x8 kf01 = *(const bf16x8*)(bb + li * 128 + ((64 + h * 16) ^ kswz));
        bf16x8 kf10 = *(const bf16x8*)(bb + 2048 + li * 128 + ((h * 16) ^ kswz));
        bf16x8 kf11 = *(const bf16x8*)(bb + 2048 + li * 128 + ((64 + h * 16) ^ kswz));
        // V^T fragments: per chunk, 2 x ds_read_b64 (conflict-free, R15 map)
        bf16x8 vf[4];
        #pragma unroll
        for (int dc = 0; dc < 4; ++dc) {
            const char* vbase = bb + 4096 + (dc * 16 + li) * 64;
            bf16x4 lo = *(const bf16x4*)(vbase + vo);
            bf16x4 hi = *(const bf16x4*)(vbase + (vo ^ 32));
            vf[dc] = __builtin_shufflevector(lo, hi, 0, 1, 2, 3, 4, 5, 6, 7);
        }
        // de-fenced: compiler emits fine-grained lgkmcnt(N) per MFMA operand

        // ---- QK^T (bias pre-loaded in accumulator), MFMA cluster boosted
        const f32x4 nb = {NBIAS, NBIAS, NBIAS, NBIAS};
        __builtin_amdgcn_s_setprio(1);
        f32x4 s0 = MFMA16(kf01, qf1, MFMA16(kf00, qf0, nb));
        f32x4 s1 = MFMA16(kf11, qf1, MFMA16(kf10, qf0, nb));
        __builtin_amdgcn_s_setprio(0);

        // ---- exponentiate (no max, no cross-lane): p = 2^(s - 46)
        bf16x8 pf;
        #pragma unroll
        for (int r = 0; r < 4; ++r) {
            pf[r]     = (__bf16)fast_exp2(s0[r]);
            pf[4 + r] = (__bf16)fast_exp2(s1[r]);
        }

        // ---- PV + l via ones-MFMA, MFMA cluster boosted
        __builtin_amdgcn_s_setprio(1);
        o0 = MFMA16(vf[0], pf, o0);
        o1 = MFMA16(vf[1], pf, o1);
        o2 = MFMA16(vf[2], pf, o2);
        o3 = MFMA16(vf[3], pf, o3);
        ol = MFMA16(ones, pf, ol);
        __builtin_amdgcn_s_setprio(0);
    };

    // end-of-iteration ordering point (single fence per iter)
    auto fence_barrier = [&]() {
        asm volatile("s_waitcnt lgkmcnt(0)" ::: "memory");
        __builtin_amdgcn_s_barrier();
    };

    // ---- prologue: tile 0 staged, tile 1 loads in flight
    load(0);
    writebuf(0);
    load(1);
    fence_barrier();

    #pragma unroll 2
    for (int t = 0; t < NT - 2; ++t) {
        writebuf((t + 1) & 1);   // write tile t+1 (regs; auto vmcnt waits)
        load(t + 2);             // issue tile t+2 loads
        body(t & 1);             // compute tile t
        fence_barrier();
    }
    // t = 30: write tile 31, no more loads
    writebuf(31 & 1);
    body(30 & 1);
    fence_barrier();
    // t = 31
    body(31 & 1);

    // ---- finalize: l replicated in ol[r] (ones-MFMA)
    const float inv_l = 1.f / ol[0];

    float* Ob = O + ((size_t)b * L_SEQ + q0) * 64;
    f32x4 ov;
    #pragma unroll
    for (int r = 0; r < 4; ++r) ov[r] = o0[r] * inv_l;
    *(f32x4*)&Ob[0 * 16 + h * 4] = ov;
    #pragma unroll
    for (int r = 0; r < 4; ++r) ov[r] = o1[r] * inv_l;
    *(f32x4*)&Ob[1 * 16 + h * 4] = ov;
    #pragma unroll
    for (int r = 0; r < 4; ++r) ov[r] = o2[r] * inv_l;
    *(f32x4*)&Ob[2 * 16 + h * 4] = ov;
    #pragma unroll
    for (int r = 0; r < 4; ++r) ov[r] = o3[r] * inv_l;
    *(f32x4*)&Ob[3 * 16 + h * 4] = ov;
}

extern "C" void kernel_launch(void* const* d_in, const int* in_sizes, int n_in,
                              void* d_out, int out_size, void* d_ws, size_t ws_size,
                              hipStream_t stream) {
    const float* q = (const float*)d_in[0];
    const float* k = (const float*)d_in[1];
    const float* v = (const float*)d_in[2];
    float* o = (float*)d_out;

    sdpa_fused<<<dim3(512), dim3(512), 0, stream>>>(q, k, v, o);
}

// Round 23
// 31.731 us; speedup vs baseline: 1.0647x; 1.0581x over previous
//
#include <hip/hip_runtime.h>
#include <hip/hip_bf16.h>

#define L_SEQ 1024
#define NT 32          // number of 32-row KV tiles

typedef __attribute__((ext_vector_type(8))) __bf16 bf16x8;
typedef __attribute__((ext_vector_type(4))) __bf16 bf16x4;
typedef __attribute__((ext_vector_type(4))) float f32x4;

__device__ __forceinline__ float fast_exp2(float x) {
#if __has_builtin(__builtin_amdgcn_exp2f)
    return __builtin_amdgcn_exp2f(x);
#else
    return exp2f(x);
#endif
}

#define MFMA16(a, b, c) __builtin_amdgcn_mfma_f32_16x16x32_bf16((a), (b), (c), 0, 0, 0)

// ---------------------------------------------------------------------------
// Round 23: halve LDS bytes per q-row. 256 blocks x 512 threads (8 waves),
// each wave owns 32 q-rows as TWO 16-row q-blocks (A at qt*256+wave*16,
// B at +128) sharing every K/V fragment read. Per-CU LDS-read traffic halves
// (16 waves x 8KB -> 8 waves x 8KB per tile: 4MB -> 2MB per CU) -- the R22
// model says this was ~2/3 of the wall at R19. Staging per block identical
// to R19 (512 threads: K quad + V 4-col per thread), now 1 stream/CU.
// Body = R19's with dual q-block MFMA/exp/PV streams (in-wave ILP replaces
// the halved TLP). De-fenced, no-max exp2 softmax (NBIAS in acc init),
// ones-MFMA l, single lgkmcnt(0)+barrier per iteration.
// ---------------------------------------------------------------------------
__global__ __launch_bounds__(512) void sdpa_fused(
    const float* __restrict__ Q, const float* __restrict__ K,
    const float* __restrict__ V, float* __restrict__ O)
{
    __shared__ __align__(16) char lds[2 * 8192];

    const int tid  = threadIdx.x;
    const int lane = tid & 63;
    const int wave = tid >> 6;       // 0..7
    const int li   = lane & 15;
    const int h    = lane >> 4;

    // XCD-chunked swizzle: 32 consecutive logical blocks per XCD.
    const int wg = blockIdx.x;
    const int lb = (wg & 7) * 32 + (wg >> 3);
    const int b  = lb >> 2;          // batch
    const int qt = lb & 3;           // 256-row q-tile
    const int qA = qt * 256 + wave * 16 + li;   // q-block B rows are qA + 128

    const float* Qb = Q + (size_t)b * L_SEQ * 64;
    const char*  Kb = (const char*)(K + (size_t)b * L_SEQ * 64);
    const float* Vf = V + (size_t)b * L_SEQ * 64;

    // ---- K staging dest offset (tile-invariant; R12 layout; 1 quad)
    int kd0;
    {
        const int qi = tid;                    // quad index 0..511
        const int r  = qi >> 4;                // kv row 0..31
        const int d4 = (qi & 15) << 2;         // d 0..60
        const int c32 = d4 >> 5, rem = d4 & 31, hf = rem >> 4, hh = (rem & 15) >> 2;
        kd0 = r * 128 + 2 * (((c32 * 32 + hh * 8) ^ ((r & 7) * 8)) + hf * 4);
    }
    // ---- V staging: column assignment + conflict-free b64 dest offset
    const int vd  = tid & 63;              // d column this thread owns
    const int vwd = 4096 + vd * 64 + 8 * (wave ^ ((vd >> 1) & 7));
    // rows covered: wave*4 .. wave*4+3

    // ---- Q fragments (both q-blocks): fold (1/temperature)*log2(e)
    const float QSC = 0.18033688011112042f;   // 0.125 * log2(e)
    bf16x8 qA0, qA1, qB0, qB1;
    {
        const float* ra = &Qb[(size_t)qA * 64];
        const float* rb = &Qb[(size_t)(qA + 128) * 64];
        f32x4 a00 = *(const f32x4*)&ra[0  + h * 4];
        f32x4 a01 = *(const f32x4*)&ra[16 + h * 4];
        f32x4 a10 = *(const f32x4*)&ra[32 + h * 4];
        f32x4 a11 = *(const f32x4*)&ra[48 + h * 4];
        f32x4 b00 = *(const f32x4*)&rb[0  + h * 4];
        f32x4 b01 = *(const f32x4*)&rb[16 + h * 4];
        f32x4 b10 = *(const f32x4*)&rb[32 + h * 4];
        f32x4 b11 = *(const f32x4*)&rb[48 + h * 4];
        #pragma unroll
        for (int j = 0; j < 4; ++j) {
            qA0[j]     = (__bf16)(a00[j] * QSC);
            qA0[4 + j] = (__bf16)(a01[j] * QSC);
            qA1[j]     = (__bf16)(a10[j] * QSC);
            qA1[4 + j] = (__bf16)(a11[j] * QSC);
            qB0[j]     = (__bf16)(b00[j] * QSC);
            qB0[4 + j] = (__bf16)(b01[j] * QSC);
            qB1[j]     = (__bf16)(b10[j] * QSC);
            qB1[4 + j] = (__bf16)(b11[j] * QSC);
        }
    }

    bf16x8 ones;
    #pragma unroll
    for (int j = 0; j < 8; ++j) ones[j] = (__bf16)1.0f;

    const float NBIAS = -46.0f;   // log2-domain bias, cancels in O = PV/l
    f32x4 oA0 = {0.f,0.f,0.f,0.f}, oA1 = {0.f,0.f,0.f,0.f};
    f32x4 oA2 = {0.f,0.f,0.f,0.f}, oA3 = {0.f,0.f,0.f,0.f};
    f32x4 oB0 = {0.f,0.f,0.f,0.f}, oB1 = {0.f,0.f,0.f,0.f};
    f32x4 oB2 = {0.f,0.f,0.f,0.f}, oB3 = {0.f,0.f,0.f,0.f};
    f32x4 olA = {0.f,0.f,0.f,0.f}, olB = {0.f,0.f,0.f,0.f};

    // ---- reg-staging: K = 1 float4 row-wise, V = 4 f32 column-wise
    f32x4 sk0, sv0;
    auto load = [&](int t) {
        const size_t tb = (size_t)t * 8192;    // bytes
        sk0 = *(const f32x4*)(Kb + tb + (tid << 4));
        const float* vcol = Vf + (size_t)t * 2048 + (size_t)(wave * 4) * 64 + vd;
        #pragma unroll
        for (int u = 0; u < 4; ++u) sv0[u] = vcol[u * 64];
    };
    auto writebuf = [&](int bi) {
        char* B = lds + bi * 8192;
        bf16x4 a, v0;
        #pragma unroll
        for (int j = 0; j < 4; ++j) { a[j] = (__bf16)sk0[j]; v0[j] = (__bf16)sv0[j]; }
        *(bf16x4*)(B + kd0) = a;
        *(bf16x4*)(B + vwd) = v0;
    };

    const int kswz = (li & 7) << 4;
    const int swr  = (li >> 1) & 7;
    const int vo   = (h ^ swr) << 3;

    auto body = [&](int bi) {
        const char* bb = lds + bi * 8192;
        // K fragments (swizzled image; shared by both q-blocks)
        bf16x8 kf00 = *(const bf16x8*)(bb + li * 128 + ((h * 16) ^ kswz));
        bf16x8 kf01 = *(const bf16x8*)(bb + li * 128 + ((64 + h * 16) ^ kswz));
        bf16x8 kf10 = *(const bf16x8*)(bb + 2048 + li * 128 + ((h * 16) ^ kswz));
        bf16x8 kf11 = *(const bf16x8*)(bb + 2048 + li * 128 + ((64 + h * 16) ^ kswz));
        // V^T fragments: per chunk, 2 x ds_read_b64 (conflict-free; shared)
        bf16x8 vf[4];
        #pragma unroll
        for (int dc = 0; dc < 4; ++dc) {
            const char* vbase = bb + 4096 + (dc * 16 + li) * 64;
            bf16x4 lo = *(const bf16x4*)(vbase + vo);
            bf16x4 hi = *(const bf16x4*)(vbase + (vo ^ 32));
            vf[dc] = __builtin_shufflevector(lo, hi, 0, 1, 2, 3, 4, 5, 6, 7);
        }
        // de-fenced: compiler emits fine-grained lgkmcnt(N) per MFMA operand

        // ---- QK^T for both q-blocks (bias pre-loaded in accumulator)
        const f32x4 nb = {NBIAS, NBIAS, NBIAS, NBIAS};
        f32x4 sA0 = MFMA16(kf01, qA1, MFMA16(kf00, qA0, nb));
        f32x4 sA1 = MFMA16(kf11, qA1, MFMA16(kf10, qA0, nb));
        f32x4 sB0 = MFMA16(kf01, qB1, MFMA16(kf00, qB0, nb));
        f32x4 sB1 = MFMA16(kf11, qB1, MFMA16(kf10, qB0, nb));

        // ---- exponentiate (no max, no cross-lane): p = 2^(s - 46)
        bf16x8 pfA, pfB;
        #pragma unroll
        for (int r = 0; r < 4; ++r) {
            pfA[r]     = (__bf16)fast_exp2(sA0[r]);
            pfA[4 + r] = (__bf16)fast_exp2(sA1[r]);
            pfB[r]     = (__bf16)fast_exp2(sB0[r]);
            pfB[4 + r] = (__bf16)fast_exp2(sB1[r]);
        }

        // ---- PV for both q-blocks + l via ones-MFMA (V frags shared)
        oA0 = MFMA16(vf[0], pfA, oA0);
        oA1 = MFMA16(vf[1], pfA, oA1);
        oA2 = MFMA16(vf[2], pfA, oA2);
        oA3 = MFMA16(vf[3], pfA, oA3);
        olA = MFMA16(ones, pfA, olA);
        oB0 = MFMA16(vf[0], pfB, oB0);
        oB1 = MFMA16(vf[1], pfB, oB1);
        oB2 = MFMA16(vf[2], pfB, oB2);
        oB3 = MFMA16(vf[3], pfB, oB3);
        olB = MFMA16(ones, pfB, olB);
    };

    // end-of-iteration ordering point (single fence per iter)
    auto fence_barrier = [&]() {
        asm volatile("s_waitcnt lgkmcnt(0)" ::: "memory");
        __builtin_amdgcn_s_barrier();
    };

    // ---- prologue: tile 0 staged, tile 1 loads in flight
    load(0);
    writebuf(0);
    load(1);
    fence_barrier();

    #pragma unroll 2
    for (int t = 0; t < NT - 2; ++t) {
        writebuf((t + 1) & 1);   // write tile t+1 (regs; auto vmcnt waits)
        load(t + 2);             // issue tile t+2 loads
        body(t & 1);             // compute tile t
        fence_barrier();
    }
    // t = 30: write tile 31, no more loads
    writebuf(31 & 1);
    body(30 & 1);
    fence_barrier();
    // t = 31
    body(31 & 1);

    // ---- finalize: l replicated in ol*[r] (ones-MFMA)
    const float ilA = 1.f / olA[0];
    const float ilB = 1.f / olB[0];

    float* ObA = O + ((size_t)b * L_SEQ + qA) * 64;
    float* ObB = ObA + 128 * 64;
    f32x4 ov;
    #pragma unroll
    for (int r = 0; r < 4; ++r) ov[r] = oA0[r] * ilA;
    *(f32x4*)&ObA[0 * 16 + h * 4] = ov;
    #pragma unroll
    for (int r = 0; r < 4; ++r) ov[r] = oA1[r] * ilA;
    *(f32x4*)&ObA[1 * 16 + h * 4] = ov;
    #pragma unroll
    for (int r = 0; r < 4; ++r) ov[r] = oA2[r] * ilA;
    *(f32x4*)&ObA[2 * 16 + h * 4] = ov;
    #pragma unroll
    for (int r = 0; r < 4; ++r) ov[r] = oA3[r] * ilA;
    *(f32x4*)&ObA[3 * 16 + h * 4] = ov;
    #pragma unroll
    for (int r = 0; r < 4; ++r) ov[r] = oB0[r] * ilB;
    *(f32x4*)&ObB[0 * 16 + h * 4] = ov;
    #pragma unroll
    for (int r = 0; r < 4; ++r) ov[r] = oB1[r] * ilB;
    *(f32x4*)&ObB[1 * 16 + h * 4] = ov;
    #pragma unroll
    for (int r = 0; r < 4; ++r) ov[r] = oB2[r] * ilB;
    *(f32x4*)&ObB[2 * 16 + h * 4] = ov;
    #pragma unroll
    for (int r = 0; r < 4; ++r) ov[r] = oB3[r] * ilB;
    *(f32x4*)&ObB[3 * 16 + h * 4] = ov;
}

extern "C" void kernel_launch(void* const* d_in, const int* in_sizes, int n_in,
                              void* d_out, int out_size, void* d_ws, size_t ws_size,
                              hipStream_t stream) {
    const float* q = (const float*)d_in[0];
    const float* k = (const float*)d_in[1];
    const float* v = (const float*)d_in[2];
    float* o = (float*)d_out;

    sdpa_fused<<<dim3(256), dim3(512), 0, stream>>>(q, k, v, o);
}

// Round 24
// 30.219 us; speedup vs baseline: 1.1180x; 1.0500x over previous
//
#include <hip/hip_runtime.h>
#include <hip/hip_bf16.h>

#define L_SEQ 1024
#define NT2 16         // number of 64-row KV tiles (2 subtiles each)

typedef __attribute__((ext_vector_type(8))) __bf16 bf16x8;
typedef __attribute__((ext_vector_type(4))) __bf16 bf16x4;
typedef __attribute__((ext_vector_type(4))) float f32x4;

__device__ __forceinline__ float fast_exp2(float x) {
#if __has_builtin(__builtin_amdgcn_exp2f)
    return __builtin_amdgcn_exp2f(x);
#else
    return exp2f(x);
#endif
}

#define MFMA16(a, b, c) __builtin_amdgcn_mfma_f32_16x16x32_bf16((a), (b), (c), 0, 0, 0)

// ---------------------------------------------------------------------------
// Round 24: R23 + TWO 32-row subtiles per barrier interval (KV step = 64).
// Each 16 KB buffer = two verbatim R19/R23-format 8 KB subtile images
// (K 4KB swizzled + V^T 4KB conflict-free), so every staging offset, read
// offset and the compute body are reused unchanged -- just executed twice
// per iteration. Rendezvous count halves: 16 fence+barrier instead of 32,
// with 2x the MFMA/exp work per interval. 256 blocks x 512 threads (8
// waves, 1 block/CU), 32 q-rows/wave (dual q-block), de-fenced, no-max
// exp2 softmax (NBIAS in acc init), ones-MFMA l.
// ---------------------------------------------------------------------------
__global__ __launch_bounds__(512) void sdpa_fused(
    const float* __restrict__ Q, const float* __restrict__ K,
    const float* __restrict__ V, float* __restrict__ O)
{
    __shared__ __align__(16) char lds[2 * 16384];   // 2 bufs x 2 subtiles x 8KB

    const int tid  = threadIdx.x;
    const int lane = tid & 63;
    const int wave = tid >> 6;       // 0..7
    const int li   = lane & 15;
    const int h    = lane >> 4;

    // XCD-chunked swizzle: 32 consecutive logical blocks per XCD.
    const int wg = blockIdx.x;
    const int lb = (wg & 7) * 32 + (wg >> 3);
    const int b  = lb >> 2;          // batch
    const int qt = lb & 3;           // 256-row q-tile
    const int qA = qt * 256 + wave * 16 + li;   // q-block B rows are qA + 128

    const float* Qb = Q + (size_t)b * L_SEQ * 64;
    const char*  Kb = (const char*)(K + (size_t)b * L_SEQ * 64);
    const float* Vf = V + (size_t)b * L_SEQ * 64;

    // ---- K staging dest offset (tile-invariant; R12 layout; 1 quad)
    int kd0;
    {
        const int qi = tid;                    // quad index 0..511
        const int r  = qi >> 4;                // kv row 0..31
        const int d4 = (qi & 15) << 2;         // d 0..60
        const int c32 = d4 >> 5, rem = d4 & 31, hf = rem >> 4, hh = (rem & 15) >> 2;
        kd0 = r * 128 + 2 * (((c32 * 32 + hh * 8) ^ ((r & 7) * 8)) + hf * 4);
    }
    // ---- V staging: column assignment + conflict-free b64 dest offset
    const int vd  = tid & 63;              // d column this thread owns
    const int vwd = 4096 + vd * 64 + 8 * (wave ^ ((vd >> 1) & 7));
    // rows covered: wave*4 .. wave*4+3

    // ---- Q fragments (both q-blocks): fold (1/temperature)*log2(e)
    const float QSC = 0.18033688011112042f;   // 0.125 * log2(e)
    bf16x8 qA0, qA1, qB0, qB1;
    {
        const float* ra = &Qb[(size_t)qA * 64];
        const float* rb = &Qb[(size_t)(qA + 128) * 64];
        f32x4 a00 = *(const f32x4*)&ra[0  + h * 4];
        f32x4 a01 = *(const f32x4*)&ra[16 + h * 4];
        f32x4 a10 = *(const f32x4*)&ra[32 + h * 4];
        f32x4 a11 = *(const f32x4*)&ra[48 + h * 4];
        f32x4 b00 = *(const f32x4*)&rb[0  + h * 4];
        f32x4 b01 = *(const f32x4*)&rb[16 + h * 4];
        f32x4 b10 = *(const f32x4*)&rb[32 + h * 4];
        f32x4 b11 = *(const f32x4*)&rb[48 + h * 4];
        #pragma unroll
        for (int j = 0; j < 4; ++j) {
            qA0[j]     = (__bf16)(a00[j] * QSC);
            qA0[4 + j] = (__bf16)(a01[j] * QSC);
            qA1[j]     = (__bf16)(a10[j] * QSC);
            qA1[4 + j] = (__bf16)(a11[j] * QSC);
            qB0[j]     = (__bf16)(b00[j] * QSC);
            qB0[4 + j] = (__bf16)(b01[j] * QSC);
            qB1[j]     = (__bf16)(b10[j] * QSC);
            qB1[4 + j] = (__bf16)(b11[j] * QSC);
        }
    }

    bf16x8 ones;
    #pragma unroll
    for (int j = 0; j < 8; ++j) ones[j] = (__bf16)1.0f;

    const float NBIAS = -46.0f;   // log2-domain bias, cancels in O = PV/l
    f32x4 oA0 = {0.f,0.f,0.f,0.f}, oA1 = {0.f,0.f,0.f,0.f};
    f32x4 oA2 = {0.f,0.f,0.f,0.f}, oA3 = {0.f,0.f,0.f,0.f};
    f32x4 oB0 = {0.f,0.f,0.f,0.f}, oB1 = {0.f,0.f,0.f,0.f};
    f32x4 oB2 = {0.f,0.f,0.f,0.f}, oB3 = {0.f,0.f,0.f,0.f};
    f32x4 olA = {0.f,0.f,0.f,0.f}, olB = {0.f,0.f,0.f,0.f};

    // ---- reg-staging for BOTH subtiles of a 64-row tile
    f32x4 sk0, sv0, sk1, sv1;
    auto load = [&](int t) {            // t = 64-row tile index, 0..15
        const size_t s0 = (size_t)(2 * t) * 8192;       // subtile 2t (K bytes)
        const size_t s1 = (size_t)(2 * t + 1) * 8192;   // subtile 2t+1
        sk0 = *(const f32x4*)(Kb + s0 + (tid << 4));
        sk1 = *(const f32x4*)(Kb + s1 + (tid << 4));
        const float* vc0 = Vf + (size_t)(2 * t) * 2048 + (size_t)(wave * 4) * 64 + vd;
        const float* vc1 = Vf + (size_t)(2 * t + 1) * 2048 + (size_t)(wave * 4) * 64 + vd;
        #pragma unroll
        for (int u = 0; u < 4; ++u) sv0[u] = vc0[u * 64];
        #pragma unroll
        for (int u = 0; u < 4; ++u) sv1[u] = vc1[u * 64];
    };
    auto writebuf = [&](int bi) {
        char* B0 = lds + bi * 16384;          // subtile image 0
        char* B1 = B0 + 8192;                 // subtile image 1
        bf16x4 a0, v0, a1, v1;
        #pragma unroll
        for (int j = 0; j < 4; ++j) {
            a0[j] = (__bf16)sk0[j]; v0[j] = (__bf16)sv0[j];
            a1[j] = (__bf16)sk1[j]; v1[j] = (__bf16)sv1[j];
        }
        *(bf16x4*)(B0 + kd0) = a0;
        *(bf16x4*)(B0 + vwd) = v0;
        *(bf16x4*)(B1 + kd0) = a1;
        *(bf16x4*)(B1 + vwd) = v1;
    };

    const int kswz = (li & 7) << 4;
    const int swr  = (li >> 1) & 7;
    const int vo   = (h ^ swr) << 3;

    // compute one 32-row subtile image at byte base `bb`
    auto bodysub = [&](const char* bb) {
        // K fragments (swizzled image; shared by both q-blocks)
        bf16x8 kf00 = *(const bf16x8*)(bb + li * 128 + ((h * 16) ^ kswz));
        bf16x8 kf01 = *(const bf16x8*)(bb + li * 128 + ((64 + h * 16) ^ kswz));
        bf16x8 kf10 = *(const bf16x8*)(bb + 2048 + li * 128 + ((h * 16) ^ kswz));
        bf16x8 kf11 = *(const bf16x8*)(bb + 2048 + li * 128 + ((64 + h * 16) ^ kswz));
        // V^T fragments: per chunk, 2 x ds_read_b64 (conflict-free; shared)
        bf16x8 vf[4];
        #pragma unroll
        for (int dc = 0; dc < 4; ++dc) {
            const char* vbase = bb + 4096 + (dc * 16 + li) * 64;
            bf16x4 lo = *(const bf16x4*)(vbase + vo);
            bf16x4 hi = *(const bf16x4*)(vbase + (vo ^ 32));
            vf[dc] = __builtin_shufflevector(lo, hi, 0, 1, 2, 3, 4, 5, 6, 7);
        }
        // de-fenced: compiler emits fine-grained lgkmcnt(N) per MFMA operand

        // ---- QK^T for both q-blocks (bias pre-loaded in accumulator)
        const f32x4 nb = {NBIAS, NBIAS, NBIAS, NBIAS};
        f32x4 sA0 = MFMA16(kf01, qA1, MFMA16(kf00, qA0, nb));
        f32x4 sA1 = MFMA16(kf11, qA1, MFMA16(kf10, qA0, nb));
        f32x4 sB0 = MFMA16(kf01, qB1, MFMA16(kf00, qB0, nb));
        f32x4 sB1 = MFMA16(kf11, qB1, MFMA16(kf10, qB0, nb));

        // ---- exponentiate (no max, no cross-lane): p = 2^(s - 46)
        bf16x8 pfA, pfB;
        #pragma unroll
        for (int r = 0; r < 4; ++r) {
            pfA[r]     = (__bf16)fast_exp2(sA0[r]);
            pfA[4 + r] = (__bf16)fast_exp2(sA1[r]);
            pfB[r]     = (__bf16)fast_exp2(sB0[r]);
            pfB[4 + r] = (__bf16)fast_exp2(sB1[r]);
        }

        // ---- PV for both q-blocks + l via ones-MFMA (V frags shared)
        oA0 = MFMA16(vf[0], pfA, oA0);
        oA1 = MFMA16(vf[1], pfA, oA1);
        oA2 = MFMA16(vf[2], pfA, oA2);
        oA3 = MFMA16(vf[3], pfA, oA3);
        olA = MFMA16(ones, pfA, olA);
        oB0 = MFMA16(vf[0], pfB, oB0);
        oB1 = MFMA16(vf[1], pfB, oB1);
        oB2 = MFMA16(vf[2], pfB, oB2);
        oB3 = MFMA16(vf[3], pfB, oB3);
        olB = MFMA16(ones, pfB, olB);
    };
    auto body = [&](int bi) {
        bodysub(lds + bi * 16384);
        bodysub(lds + bi * 16384 + 8192);
    };

    // end-of-iteration ordering point (single fence per iter; 16 total)
    auto fence_barrier = [&]() {
        asm volatile("s_waitcnt lgkmcnt(0)" ::: "memory");
        __builtin_amdgcn_s_barrier();
    };

    // ---- prologue: tile 0 staged, tile 1 loads in flight
    load(0);
    writebuf(0);
    load(1);
    fence_barrier();

    #pragma unroll 2
    for (int t = 0; t < NT2 - 2; ++t) {
        writebuf((t + 1) & 1);   // write tile t+1 (regs; auto vmcnt waits)
        load(t + 2);             // issue tile t+2 loads
        body(t & 1);             // compute tile t (both subtiles)
        fence_barrier();
    }
    // t = 14: write tile 15, no more loads
    writebuf(15 & 1);
    body(14 & 1);
    fence_barrier();
    // t = 15
    body(15 & 1);

    // ---- finalize: l replicated in ol*[r] (ones-MFMA)
    const float ilA = 1.f / olA[0];
    const float ilB = 1.f / olB[0];

    float* ObA = O + ((size_t)b * L_SEQ + qA) * 64;
    float* ObB = ObA + 128 * 64;
    f32x4 ov;
    #pragma unroll
    for (int r = 0; r < 4; ++r) ov[r] = oA0[r] * ilA;
    *(f32x4*)&ObA[0 * 16 + h * 4] = ov;
    #pragma unroll
    for (int r = 0; r < 4; ++r) ov[r] = oA1[r] * ilA;
    *(f32x4*)&ObA[1 * 16 + h * 4] = ov;
    #pragma unroll
    for (int r = 0; r < 4; ++r) ov[r] = oA2[r] * ilA;
    *(f32x4*)&ObA[2 * 16 + h * 4] = ov;
    #pragma unroll
    for (int r = 0; r < 4; ++r) ov[r] = oA3[r] * ilA;
    *(f32x4*)&ObA[3 * 16 + h * 4] = ov;
    #pragma unroll
    for (int r = 0; r < 4; ++r) ov[r] = oB0[r] * ilB;
    *(f32x4*)&ObB[0 * 16 + h * 4] = ov;
    #pragma unroll
    for (int r = 0; r < 4; ++r) ov[r] = oB1[r] * ilB;
    *(f32x4*)&ObB[1 * 16 + h * 4] = ov;
    #pragma unroll
    for (int r = 0; r < 4; ++r) ov[r] = oB2[r] * ilB;
    *(f32x4*)&ObB[2 * 16 + h * 4] = ov;
    #pragma unroll
    for (int r = 0; r < 4; ++r) ov[r] = oB3[r] * ilB;
    *(f32x4*)&ObB[3 * 16 + h * 4] = ov;
}

extern "C" void kernel_launch(void* const* d_in, const int* in_sizes, int n_in,
                              void* d_out, int out_size, void* d_ws, size_t ws_size,
                              hipStream_t stream) {
    const float* q = (const float*)d_in[0];
    const float* k = (const float*)d_in[1];
    const float* v = (const float*)d_in[2];
    float* o = (float*)d_out;

    sdpa_fused<<<dim3(256), dim3(512), 0, stream>>>(q, k, v, o);
}

// Round 25
// 30.206 us; speedup vs baseline: 1.1185x; 1.0004x over previous
//
#include <hip/hip_runtime.h>
#include <hip/hip_bf16.h>

#define L_SEQ 1024
#define NT4 8          // number of 128-row KV tiles (4 subtiles each)

typedef __attribute__((ext_vector_type(8))) __bf16 bf16x8;
typedef __attribute__((ext_vector_type(4))) __bf16 bf16x4;
typedef __attribute__((ext_vector_type(4))) float f32x4;

__device__ __forceinline__ float fast_exp2(float x) {
#if __has_builtin(__builtin_amdgcn_exp2f)
    return __builtin_amdgcn_exp2f(x);
#else
    return exp2f(x);
#endif
}

#define MFMA16(a, b, c) __builtin_amdgcn_mfma_f32_16x16x32_bf16((a), (b), (c), 0, 0, 0)

// ---------------------------------------------------------------------------
// Round 25: R24 with FOUR 32-row subtiles per barrier interval (KV step=128).
// Each 32 KB buffer = four verbatim 8 KB subtile images (K 4KB swizzled +
// V^T 4KB conflict-free); staging offsets, read offsets and the subtile
// compute body are unchanged -- executed 4x per iteration. Rendezvous count
// halves again: 8 fence+barrier total (was 16 in R24, 32 in R23).
// LDS = 2 x 32KB = 64KB (still 1 block/CU, unchanged since R23).
// 256 blocks x 512 threads (8 waves), 32 q-rows/wave (dual q-block),
// de-fenced, no-max exp2 softmax (NBIAS in acc init), ones-MFMA l.
// All staging register sets are named/compile-time-indexed (rule #20).
// ---------------------------------------------------------------------------
__global__ __launch_bounds__(512) void sdpa_fused(
    const float* __restrict__ Q, const float* __restrict__ K,
    const float* __restrict__ V, float* __restrict__ O)
{
    __shared__ __align__(16) char lds[2 * 32768];   // 2 bufs x 4 subtiles x 8KB

    const int tid  = threadIdx.x;
    const int lane = tid & 63;
    const int wave = tid >> 6;       // 0..7
    const int li   = lane & 15;
    const int h    = lane >> 4;

    // XCD-chunked swizzle: 32 consecutive logical blocks per XCD.
    const int wg = blockIdx.x;
    const int lb = (wg & 7) * 32 + (wg >> 3);
    const int b  = lb >> 2;          // batch
    const int qt = lb & 3;           // 256-row q-tile
    const int qA = qt * 256 + wave * 16 + li;   // q-block B rows are qA + 128

    const float* Qb = Q + (size_t)b * L_SEQ * 64;
    const char*  Kb = (const char*)(K + (size_t)b * L_SEQ * 64);
    const float* Vf = V + (size_t)b * L_SEQ * 64;

    // ---- K staging dest offset (tile-invariant; R12 layout; 1 quad)
    int kd0;
    {
        const int qi = tid;                    // quad index 0..511
        const int r  = qi >> 4;                // kv row 0..31
        const int d4 = (qi & 15) << 2;         // d 0..60
        const int c32 = d4 >> 5, rem = d4 & 31, hf = rem >> 4, hh = (rem & 15) >> 2;
        kd0 = r * 128 + 2 * (((c32 * 32 + hh * 8) ^ ((r & 7) * 8)) + hf * 4);
    }
    // ---- V staging: column assignment + conflict-free b64 dest offset
    const int vd  = tid & 63;              // d column this thread owns
    const int vwd = 4096 + vd * 64 + 8 * (wave ^ ((vd >> 1) & 7));
    // rows covered: wave*4 .. wave*4+3

    // ---- Q fragments (both q-blocks): fold (1/temperature)*log2(e)
    const float QSC = 0.18033688011112042f;   // 0.125 * log2(e)
    bf16x8 qA0, qA1, qB0, qB1;
    {
        const float* ra = &Qb[(size_t)qA * 64];
        const float* rb = &Qb[(size_t)(qA + 128) * 64];
        f32x4 a00 = *(const f32x4*)&ra[0  + h * 4];
        f32x4 a01 = *(const f32x4*)&ra[16 + h * 4];
        f32x4 a10 = *(const f32x4*)&ra[32 + h * 4];
        f32x4 a11 = *(const f32x4*)&ra[48 + h * 4];
        f32x4 b00 = *(const f32x4*)&rb[0  + h * 4];
        f32x4 b01 = *(const f32x4*)&rb[16 + h * 4];
        f32x4 b10 = *(const f32x4*)&rb[32 + h * 4];
        f32x4 b11 = *(const f32x4*)&rb[48 + h * 4];
        #pragma unroll
        for (int j = 0; j < 4; ++j) {
            qA0[j]     = (__bf16)(a00[j] * QSC);
            qA0[4 + j] = (__bf16)(a01[j] * QSC);
            qA1[j]     = (__bf16)(a10[j] * QSC);
            qA1[4 + j] = (__bf16)(a11[j] * QSC);
            qB0[j]     = (__bf16)(b00[j] * QSC);
            qB0[4 + j] = (__bf16)(b01[j] * QSC);
            qB1[j]     = (__bf16)(b10[j] * QSC);
            qB1[4 + j] = (__bf16)(b11[j] * QSC);
        }
    }

    bf16x8 ones;
    #pragma unroll
    for (int j = 0; j < 8; ++j) ones[j] = (__bf16)1.0f;

    const float NBIAS = -46.0f;   // log2-domain bias, cancels in O = PV/l
    f32x4 oA0 = {0.f,0.f,0.f,0.f}, oA1 = {0.f,0.f,0.f,0.f};
    f32x4 oA2 = {0.f,0.f,0.f,0.f}, oA3 = {0.f,0.f,0.f,0.f};
    f32x4 oB0 = {0.f,0.f,0.f,0.f}, oB1 = {0.f,0.f,0.f,0.f};
    f32x4 oB2 = {0.f,0.f,0.f,0.f}, oB3 = {0.f,0.f,0.f,0.f};
    f32x4 olA = {0.f,0.f,0.f,0.f}, olB = {0.f,0.f,0.f,0.f};

    // ---- reg-staging for FOUR subtiles of a 128-row tile (unrolled indices)
    f32x4 sk[4], sv[4];
    auto load = [&](int t) {            // t = 128-row tile index, 0..7
        #pragma unroll
        for (int s = 0; s < 4; ++s) {
            const size_t sb = (size_t)(4 * t + s) * 8192;   // subtile K bytes
            sk[s] = *(const f32x4*)(Kb + sb + (tid << 4));
            const float* vc = Vf + (size_t)(4 * t + s) * 2048
                              + (size_t)(wave * 4) * 64 + vd;
            #pragma unroll
            for (int u = 0; u < 4; ++u) sv[s][u] = vc[u * 64];
        }
    };
    auto writebuf = [&](int bi) {
        #pragma unroll
        for (int s = 0; s < 4; ++s) {
            char* B = lds + bi * 32768 + s * 8192;
            bf16x4 a, v0;
            #pragma unroll
            for (int j = 0; j < 4; ++j) {
                a[j]  = (__bf16)sk[s][j];
                v0[j] = (__bf16)sv[s][j];
            }
            *(bf16x4*)(B + kd0) = a;
            *(bf16x4*)(B + vwd) = v0;
        }
    };

    const int kswz = (li & 7) << 4;
    const int swr  = (li >> 1) & 7;
    const int vo   = (h ^ swr) << 3;

    // compute one 32-row subtile image at byte base `bb`
    auto bodysub = [&](const char* bb) {
        // K fragments (swizzled image; shared by both q-blocks)
        bf16x8 kf00 = *(const bf16x8*)(bb + li * 128 + ((h * 16) ^ kswz));
        bf16x8 kf01 = *(const bf16x8*)(bb + li * 128 + ((64 + h * 16) ^ kswz));
        bf16x8 kf10 = *(const bf16x8*)(bb + 2048 + li * 128 + ((h * 16) ^ kswz));
        bf16x8 kf11 = *(const bf16x8*)(bb + 2048 + li * 128 + ((64 + h * 16) ^ kswz));
        // V^T fragments: per chunk, 2 x ds_read_b64 (conflict-free; shared)
        bf16x8 vf[4];
        #pragma unroll
        for (int dc = 0; dc < 4; ++dc) {
            const char* vbase = bb + 4096 + (dc * 16 + li) * 64;
            bf16x4 lo = *(const bf16x4*)(vbase + vo);
            bf16x4 hi = *(const bf16x4*)(vbase + (vo ^ 32));
            vf[dc] = __builtin_shufflevector(lo, hi, 0, 1, 2, 3, 4, 5, 6, 7);
        }
        // de-fenced: compiler emits fine-grained lgkmcnt(N) per MFMA operand

        // ---- QK^T for both q-blocks (bias pre-loaded in accumulator)
        const f32x4 nb = {NBIAS, NBIAS, NBIAS, NBIAS};
        f32x4 sA0 = MFMA16(kf01, qA1, MFMA16(kf00, qA0, nb));
        f32x4 sA1 = MFMA16(kf11, qA1, MFMA16(kf10, qA0, nb));
        f32x4 sB0 = MFMA16(kf01, qB1, MFMA16(kf00, qB0, nb));
        f32x4 sB1 = MFMA16(kf11, qB1, MFMA16(kf10, qB0, nb));

        // ---- exponentiate (no max, no cross-lane): p = 2^(s - 46)
        bf16x8 pfA, pfB;
        #pragma unroll
        for (int r = 0; r < 4; ++r) {
            pfA[r]     = (__bf16)fast_exp2(sA0[r]);
            pfA[4 + r] = (__bf16)fast_exp2(sA1[r]);
            pfB[r]     = (__bf16)fast_exp2(sB0[r]);
            pfB[4 + r] = (__bf16)fast_exp2(sB1[r]);
        }

        // ---- PV for both q-blocks + l via ones-MFMA (V frags shared)
        oA0 = MFMA16(vf[0], pfA, oA0);
        oA1 = MFMA16(vf[1], pfA, oA1);
        oA2 = MFMA16(vf[2], pfA, oA2);
        oA3 = MFMA16(vf[3], pfA, oA3);
        olA = MFMA16(ones, pfA, olA);
        oB0 = MFMA16(vf[0], pfB, oB0);
        oB1 = MFMA16(vf[1], pfB, oB1);
        oB2 = MFMA16(vf[2], pfB, oB2);
        oB3 = MFMA16(vf[3], pfB, oB3);
        olB = MFMA16(ones, pfB, olB);
    };
    auto body = [&](int bi) {
        #pragma unroll
        for (int s = 0; s < 4; ++s)
            bodysub(lds + bi * 32768 + s * 8192);
    };

    // end-of-iteration ordering point (single fence per iter; 8 total)
    auto fence_barrier = [&]() {
        asm volatile("s_waitcnt lgkmcnt(0)" ::: "memory");
        __builtin_amdgcn_s_barrier();
    };

    // ---- prologue: tile 0 staged, tile 1 loads in flight
    load(0);
    writebuf(0);
    load(1);
    fence_barrier();

    for (int t = 0; t < NT4 - 2; ++t) {
        writebuf((t + 1) & 1);   // write tile t+1 (regs; auto vmcnt waits)
        load(t + 2);             // issue tile t+2 loads
        body(t & 1);             // compute tile t (4 subtiles)
        fence_barrier();
    }
    // t = 6: write tile 7, no more loads
    writebuf(7 & 1);
    body(6 & 1);
    fence_barrier();
    // t = 7
    body(7 & 1);

    // ---- finalize: l replicated in ol*[r] (ones-MFMA)
    const float ilA = 1.f / olA[0];
    const float ilB = 1.f / olB[0];

    float* ObA = O + ((size_t)b * L_SEQ + qA) * 64;
    float* ObB = ObA + 128 * 64;
    f32x4 ov;
    #pragma unroll
    for (int r = 0; r < 4; ++r) ov[r] = oA0[r] * ilA;
    *(f32x4*)&ObA[0 * 16 + h * 4] = ov;
    #pragma unroll
    for (int r = 0; r < 4; ++r) ov[r] = oA1[r] * ilA;
    *(f32x4*)&ObA[1 * 16 + h * 4] = ov;
    #pragma unroll
    for (int r = 0; r < 4; ++r) ov[r] = oA2[r] * ilA;
    *(f32x4*)&ObA[2 * 16 + h * 4] = ov;
    #pragma unroll
    for (int r = 0; r < 4; ++r) ov[r] = oA3[r] * ilA;
    *(f32x4*)&ObA[3 * 16 + h * 4] = ov;
    #pragma unroll
    for (int r = 0; r < 4; ++r) ov[r] = oB0[r] * ilB;
    *(f32x4*)&ObB[0 * 16 + h * 4] = ov;
    #pragma unroll
    for (int r = 0; r < 4; ++r) ov[r] = oB1[r] * ilB;
    *(f32x4*)&ObB[1 * 16 + h * 4] = ov;
    #pragma unroll
    for (int r = 0; r < 4; ++r) ov[r] = oB2[r] * ilB;
    *(f32x4*)&ObB[2 * 16 + h * 4] = ov;
    #pragma unroll
    for (int r = 0; r < 4; ++r) ov[r] = oB3[r] * ilB;
    *(f32x4*)&ObB[3 * 16 + h * 4] = ov;
}

extern "C" void kernel_launch(void* const* d_in, const int* in_sizes, int n_in,
                              void* d_out, int out_size, void* d_ws, size_t ws_size,
                              hipStream_t stream) {
    const float* q = (const float*)d_in[0];
    const float* k = (const float*)d_in[1];
    const float* v = (const float*)d_in[2];
    float* o = (float*)d_out;

    sdpa_fused<<<dim3(256), dim3(512), 0, stream>>>(q, k, v, o);
}